// Round 1
// baseline (895.367 us; speedup 1.0000x reference)
//
#include <hip/hip_runtime.h>
#include <cstdint>
#include <cstddef>

#define N_NODES 100000
#define N_EDGES 1600000

constexpr int SCAN_CHUNK = 1024;
constexpr int NUM_CHUNKS = (N_NODES + SCAN_CHUNK - 1) / SCAN_CHUNK;  // 98

// ---------------------------------------------------------------- CSR build
__global__ void count_kernel(const int* __restrict__ dst, int* __restrict__ counts) {
    int e = blockIdx.x * 256 + threadIdx.x;
    if (e < N_EDGES) atomicAdd(&counts[dst[e]], 1);
}

__global__ void scan1_kernel(const int* __restrict__ counts, int* __restrict__ chunkSums) {
    __shared__ int sdata[256];
    int t = threadIdx.x;
    int base = blockIdx.x * SCAN_CHUNK + t * 4;
    int s = 0;
#pragma unroll
    for (int j = 0; j < 4; ++j) {
        int idx = base + j;
        if (idx < N_NODES) s += counts[idx];
    }
    sdata[t] = s;
    __syncthreads();
    for (int off = 128; off > 0; off >>= 1) {
        if (t < off) sdata[t] += sdata[t + off];
        __syncthreads();
    }
    if (t == 0) chunkSums[blockIdx.x] = sdata[0];
}

__global__ void scan2_kernel(const int* __restrict__ chunkSums, int* __restrict__ chunkOff,
                             int* __restrict__ rowStart) {
    int run = 0;
    for (int i = 0; i < NUM_CHUNKS; ++i) {
        chunkOff[i] = run;
        run += chunkSums[i];
    }
    rowStart[N_NODES] = run;  // == N_EDGES
}

__global__ void scan3_kernel(const int* __restrict__ counts, const int* __restrict__ chunkOff,
                             int* __restrict__ rowStart) {
    __shared__ int sdata[256];
    int t = threadIdx.x;
    int base = blockIdx.x * SCAN_CHUNK + t * 4;
    int c[4];
    int s = 0;
#pragma unroll
    for (int j = 0; j < 4; ++j) {
        int idx = base + j;
        c[j] = (idx < N_NODES) ? counts[idx] : 0;
        s += c[j];
    }
    int mySum = s;
    sdata[t] = s;
    __syncthreads();
    for (int off = 1; off < 256; off <<= 1) {
        int v = (t >= off) ? sdata[t - off] : 0;
        __syncthreads();
        sdata[t] += v;
        __syncthreads();
    }
    int excl = sdata[t] - mySum + chunkOff[blockIdx.x];
#pragma unroll
    for (int j = 0; j < 4; ++j) {
        int idx = base + j;
        if (idx < N_NODES) {
            rowStart[idx] = excl;
            excl += c[j];
        }
    }
}

__global__ void norm_kernel(const int* __restrict__ counts, float* __restrict__ normv,
                            float* __restrict__ deginv) {
    int i = blockIdx.x * 256 + threadIdx.x;
    if (i < N_NODES) {
        double d = (double)(counts[i] + 1);  // +1 self loop
        normv[i]  = (float)(1.0 / sqrt(d));
        deginv[i] = (float)(1.0 / d);
    }
}

__global__ void fill_kernel(const int* __restrict__ src, const int* __restrict__ dst,
                            int* __restrict__ cursor, int* __restrict__ colIdx) {
    int e = blockIdx.x * 256 + threadIdx.x;
    if (e < N_EDGES) {
        int p = atomicAdd(&cursor[dst[e]], 1);
        colIdx[p] = src[e];
    }
}

// ---------------------------------------------------------------- fp32 GEMM
// C[M,128] = A[M,K] @ W[K,128] (+ bias). BM=128, BN=128, BK=32, 256 thr, 8x8/thr.
__global__ __launch_bounds__(256) void gemm_kernel(const float* __restrict__ A,
                                                   const float* __restrict__ W,
                                                   const float* __restrict__ bias,
                                                   float* __restrict__ C, int M, int K) {
    __shared__ float sA[32][132];  // transposed: sA[k][m], pad 4 to keep 16B align
    __shared__ float sB[32][128];  // sB[k][n]
    const int t = threadIdx.x;
    const int row0 = blockIdx.x * 128;
    const int tx = t & 15;   // col group: cols tx*8 .. tx*8+7
    const int ty = t >> 4;   // row group: rows ty*8 .. ty*8+7

    float acc[8][8];
#pragma unroll
    for (int i = 0; i < 8; ++i)
#pragma unroll
        for (int j = 0; j < 8; ++j) acc[i][j] = 0.f;

    for (int k0 = 0; k0 < K; k0 += 32) {
        // stage A tile (transposed)
#pragma unroll
        for (int i = 0; i < 4; ++i) {
            int id = t + i * 256;
            int r = id >> 3;       // 0..127
            int cq = id & 7;       // k-quad 0..7
            int gr = row0 + r;
            float4 v = make_float4(0.f, 0.f, 0.f, 0.f);
            if (gr < M) v = *(const float4*)(A + (size_t)gr * K + k0 + cq * 4);
            sA[cq * 4 + 0][r] = v.x;
            sA[cq * 4 + 1][r] = v.y;
            sA[cq * 4 + 2][r] = v.z;
            sA[cq * 4 + 3][r] = v.w;
        }
        // stage W tile
#pragma unroll
        for (int i = 0; i < 4; ++i) {
            int id = t + i * 256;
            int kr = id >> 5;      // 0..31
            int cq = id & 31;      // 0..31
            *(float4*)&sB[kr][cq * 4] = *(const float4*)(W + (size_t)(k0 + kr) * 128 + cq * 4);
        }
        __syncthreads();
#pragma unroll
        for (int kk = 0; kk < 32; ++kk) {
            float a[8], b[8];
            *(float4*)&a[0] = *(const float4*)&sA[kk][ty * 8];
            *(float4*)&a[4] = *(const float4*)&sA[kk][ty * 8 + 4];
            *(float4*)&b[0] = *(const float4*)&sB[kk][tx * 8];
            *(float4*)&b[4] = *(const float4*)&sB[kk][tx * 8 + 4];
#pragma unroll
            for (int i = 0; i < 8; ++i)
#pragma unroll
                for (int j = 0; j < 8; ++j) acc[i][j] = fmaf(a[i], b[j], acc[i][j]);
        }
        __syncthreads();
    }

    float bv[8];
#pragma unroll
    for (int j = 0; j < 8; ++j) bv[j] = bias ? bias[tx * 8 + j] : 0.f;

#pragma unroll
    for (int i = 0; i < 8; ++i) {
        int r = row0 + ty * 8 + i;
        if (r >= M) continue;
        float* cp = C + (size_t)r * 128 + tx * 8;
        float4 o0, o1;
        o0.x = acc[i][0] + bv[0]; o0.y = acc[i][1] + bv[1];
        o0.z = acc[i][2] + bv[2]; o0.w = acc[i][3] + bv[3];
        o1.x = acc[i][4] + bv[4]; o1.y = acc[i][5] + bv[5];
        o1.z = acc[i][6] + bv[6]; o1.w = acc[i][7] + bv[7];
        *(float4*)cp = o0;
        *(float4*)(cp + 4) = o1;
    }
}

// ------------------------------------------------------------- aggregation
// out[i] = maybe_relu( norm[i] * sum_{e: dst=i} norm[src]*z[src] + deg_inv[i]*z[i] + b )
// one wave (64 lanes) per node, float2 per lane over 128 cols.
__global__ __launch_bounds__(256) void agg_kernel(const float* __restrict__ z,
                                                  const int* __restrict__ rowStart,
                                                  const int* __restrict__ colIdx,
                                                  const float* __restrict__ normv,
                                                  const float* __restrict__ deginv,
                                                  const float* __restrict__ bias,
                                                  float* __restrict__ out, int doRelu) {
    int wid = (blockIdx.x * 256 + threadIdx.x) >> 6;  // node id
    int lane = threadIdx.x & 63;
    if (wid >= N_NODES) return;
    int s0 = rowStart[wid];
    int s1 = rowStart[wid + 1];
    const int c = lane * 2;
    float2 acc = make_float2(0.f, 0.f);
    for (int e = s0; e < s1; ++e) {
        int srcn = colIdx[e];
        float w = normv[srcn];
        float2 zv = *(const float2*)(z + (size_t)srcn * 128 + c);
        acc.x = fmaf(w, zv.x, acc.x);
        acc.y = fmaf(w, zv.y, acc.y);
    }
    float nd = normv[wid];
    float di = deginv[wid];
    float2 zd = *(const float2*)(z + (size_t)wid * 128 + c);
    float2 o;
    o.x = fmaf(nd, acc.x, fmaf(di, zd.x, bias[c]));
    o.y = fmaf(nd, acc.y, fmaf(di, zd.y, bias[c + 1]));
    if (doRelu) {
        o.x = fmaxf(o.x, 0.f);
        o.y = fmaxf(o.y, 0.f);
    }
    *(float2*)(out + (size_t)wid * 128 + c) = o;
}

// ---------------------------------------------------------------- launcher
extern "C" void kernel_launch(void* const* d_in, const int* in_sizes, int n_in,
                              void* d_out, int out_size, void* d_ws, size_t ws_size,
                              hipStream_t stream) {
    const float* x  = (const float*)d_in[0];
    const int* ei   = (const int*)d_in[1];
    const float* Wp = (const float*)d_in[2];
    const float* bp = (const float*)d_in[3];
    const float* W1 = (const float*)d_in[4];
    const float* b1 = (const float*)d_in[5];
    const float* W2 = (const float*)d_in[6];
    const float* b2 = (const float*)d_in[7];
    float* out = (float*)d_out;

    const int* srcIdx = ei;             // edge_index[0]
    const int* dstIdx = ei + N_EDGES;   // edge_index[1]

    // workspace carve-up (512B aligned slices)
    size_t off = 0;
    auto alloc = [&](size_t bytes) -> void* {
        void* p = (char*)d_ws + off;
        off += (bytes + 511) & ~(size_t)511;
        return p;
    };
    int* counts    = (int*)alloc((size_t)N_NODES * 4);
    int* rowStart  = (int*)alloc((size_t)(N_NODES + 1) * 4);
    int* cursor    = (int*)alloc((size_t)N_NODES * 4);
    int* colIdx    = (int*)alloc((size_t)N_EDGES * 4);
    int* chunkSums = (int*)alloc((size_t)NUM_CHUNKS * 4);
    int* chunkOff  = (int*)alloc((size_t)NUM_CHUNKS * 4);
    float* normv   = (float*)alloc((size_t)N_NODES * 4);
    float* deginv  = (float*)alloc((size_t)N_NODES * 4);
    float* h       = (float*)alloc((size_t)N_NODES * 128 * 4);
    float* zA      = (float*)alloc((size_t)N_NODES * 128 * 4);
    float* zB      = (float*)alloc((size_t)N_NODES * 128 * 4);

    const int EB = (N_EDGES + 255) / 256;       // 6250
    const int NBn = (N_NODES + 255) / 256;      // 391
    const int GB = (N_NODES + 127) / 128;       // 782 gemm blocks
    const int AB = (N_NODES + 3) / 4;           // 25000 agg blocks (4 waves/block)

    // ---- CSR build (per call; ws is re-poisoned every launch) ----
    hipMemsetAsync(counts, 0, (size_t)N_NODES * 4, stream);
    count_kernel<<<EB, 256, 0, stream>>>(dstIdx, counts);
    scan1_kernel<<<NUM_CHUNKS, 256, 0, stream>>>(counts, chunkSums);
    scan2_kernel<<<1, 1, 0, stream>>>(chunkSums, chunkOff, rowStart);
    scan3_kernel<<<NUM_CHUNKS, 256, 0, stream>>>(counts, chunkOff, rowStart);
    norm_kernel<<<NBn, 256, 0, stream>>>(counts, normv, deginv);
    hipMemcpyAsync(cursor, rowStart, (size_t)N_NODES * 4, hipMemcpyDeviceToDevice, stream);
    fill_kernel<<<EB, 256, 0, stream>>>(srcIdx, dstIdx, cursor, colIdx);

    // ---- dense + sparse pipeline ----
    // h = x @ Wp + bp
    gemm_kernel<<<GB, 256, 0, stream>>>(x, Wp, bp, h, N_NODES, 256);
    // zA = h @ W1
    gemm_kernel<<<GB, 256, 0, stream>>>(h, W1, nullptr, zA, N_NODES, 128);
    // zB = relu(agg(zA) + zA*deg_inv + b1)
    agg_kernel<<<AB, 256, 0, stream>>>(zA, rowStart, colIdx, normv, deginv, b1, zB, 1);
    // h (reused) = zB @ W2
    gemm_kernel<<<GB, 256, 0, stream>>>(zB, W2, nullptr, h, N_NODES, 128);
    // out = agg(h) + h*deg_inv + b2
    agg_kernel<<<AB, 256, 0, stream>>>(h, rowStart, colIdx, normv, deginv, b2, out, 0);
}

// Round 2
// 743.266 us; speedup vs baseline: 1.2046x; 1.2046x over previous
//
#include <hip/hip_runtime.h>
#include <cstdint>
#include <cstddef>

#define N_NODES 100000
#define N_EDGES 1600000

constexpr int SCAN_CHUNK = 1024;
constexpr int NUM_CHUNKS = (N_NODES + SCAN_CHUNK - 1) / SCAN_CHUNK;  // 98

// ---------------------------------------------------------------- CSR build
__global__ void count_kernel(const int* __restrict__ dst, int* __restrict__ counts) {
    int e = blockIdx.x * 256 + threadIdx.x;
    if (e < N_EDGES) atomicAdd(&counts[dst[e]], 1);
}

__global__ void scan1_kernel(const int* __restrict__ counts, int* __restrict__ chunkSums) {
    __shared__ int sdata[256];
    int t = threadIdx.x;
    int base = blockIdx.x * SCAN_CHUNK + t * 4;
    int s = 0;
#pragma unroll
    for (int j = 0; j < 4; ++j) {
        int idx = base + j;
        if (idx < N_NODES) s += counts[idx];
    }
    sdata[t] = s;
    __syncthreads();
    for (int off = 128; off > 0; off >>= 1) {
        if (t < off) sdata[t] += sdata[t + off];
        __syncthreads();
    }
    if (t == 0) chunkSums[blockIdx.x] = sdata[0];
}

__global__ void scan2_kernel(const int* __restrict__ chunkSums, int* __restrict__ chunkOff,
                             int* __restrict__ rowStart) {
    int run = 0;
    for (int i = 0; i < NUM_CHUNKS; ++i) {
        chunkOff[i] = run;
        run += chunkSums[i];
    }
    rowStart[N_NODES] = run;  // == N_EDGES
}

__global__ void scan3_kernel(const int* __restrict__ counts, const int* __restrict__ chunkOff,
                             int* __restrict__ rowStart) {
    __shared__ int sdata[256];
    int t = threadIdx.x;
    int base = blockIdx.x * SCAN_CHUNK + t * 4;
    int c[4];
    int s = 0;
#pragma unroll
    for (int j = 0; j < 4; ++j) {
        int idx = base + j;
        c[j] = (idx < N_NODES) ? counts[idx] : 0;
        s += c[j];
    }
    int mySum = s;
    sdata[t] = s;
    __syncthreads();
    for (int off = 1; off < 256; off <<= 1) {
        int v = (t >= off) ? sdata[t - off] : 0;
        __syncthreads();
        sdata[t] += v;
        __syncthreads();
    }
    int excl = sdata[t] - mySum + chunkOff[blockIdx.x];
#pragma unroll
    for (int j = 0; j < 4; ++j) {
        int idx = base + j;
        if (idx < N_NODES) {
            rowStart[idx] = excl;
            excl += c[j];
        }
    }
}

__global__ void norm_kernel(const int* __restrict__ counts, float* __restrict__ normv) {
    int i = blockIdx.x * 256 + threadIdx.x;
    if (i < N_NODES) {
        double d = (double)(counts[i] + 1);  // +1 self loop
        normv[i] = (float)(1.0 / sqrt(d));
    }
}

__global__ void fill_kernel(const int* __restrict__ src, const int* __restrict__ dst,
                            int* __restrict__ cursor, int* __restrict__ colIdx) {
    int e = blockIdx.x * 256 + threadIdx.x;
    if (e < N_EDGES) {
        int p = atomicAdd(&cursor[dst[e]], 1);
        colIdx[p] = src[e];
    }
}

// ------------------------------------------------- Wc = Wp@W1, bc = bp@W1
__global__ void wc_kernel(const float* __restrict__ Wp, const float* __restrict__ bp,
                          const float* __restrict__ W1, float* __restrict__ Wc,
                          float* __restrict__ bc) {
    int r = blockIdx.x;       // 0..255 => Wc row; 256 => bias row
    int cc = threadIdx.x;     // 0..127
    float acc = 0.f;
    if (r < 256) {
        for (int k = 0; k < 128; ++k) acc = fmaf(Wp[r * 128 + k], W1[k * 128 + cc], acc);
        Wc[r * 128 + cc] = acc;
    } else {
        for (int k = 0; k < 128; ++k) acc = fmaf(bp[k], W1[k * 128 + cc], acc);
        bc[cc] = acc;
    }
}

// ---------------------------------------------------------------- fp32 GEMM
// C[r][c] = (sum_k A[r][k]*W[k][c] + bias[c]) * scale[r]
// BM=128, BN=128, BK=32, 256 thr, 8x8/thr.
__global__ __launch_bounds__(256) void gemm_kernel(const float* __restrict__ A,
                                                   const float* __restrict__ W,
                                                   const float* __restrict__ bias,
                                                   const float* __restrict__ scale,
                                                   float* __restrict__ C, int M, int K) {
    __shared__ float sA[32][132];  // transposed: sA[k][m]
    __shared__ float sB[32][128];  // sB[k][n]
    const int t = threadIdx.x;
    const int row0 = blockIdx.x * 128;
    const int tx = t & 15;   // cols tx*8 .. tx*8+7
    const int ty = t >> 4;   // rows ty*8 .. ty*8+7

    float acc[8][8];
#pragma unroll
    for (int i = 0; i < 8; ++i)
#pragma unroll
        for (int j = 0; j < 8; ++j) acc[i][j] = 0.f;

    for (int k0 = 0; k0 < K; k0 += 32) {
#pragma unroll
        for (int i = 0; i < 4; ++i) {
            int id = t + i * 256;
            int r = id >> 3;
            int cq = id & 7;
            int gr = row0 + r;
            float4 v = make_float4(0.f, 0.f, 0.f, 0.f);
            if (gr < M) v = *(const float4*)(A + (size_t)gr * K + k0 + cq * 4);
            sA[cq * 4 + 0][r] = v.x;
            sA[cq * 4 + 1][r] = v.y;
            sA[cq * 4 + 2][r] = v.z;
            sA[cq * 4 + 3][r] = v.w;
        }
#pragma unroll
        for (int i = 0; i < 4; ++i) {
            int id = t + i * 256;
            int kr = id >> 5;
            int cq = id & 31;
            *(float4*)&sB[kr][cq * 4] = *(const float4*)(W + (size_t)(k0 + kr) * 128 + cq * 4);
        }
        __syncthreads();
#pragma unroll
        for (int kk = 0; kk < 32; ++kk) {
            float a[8], b[8];
            *(float4*)&a[0] = *(const float4*)&sA[kk][ty * 8];
            *(float4*)&a[4] = *(const float4*)&sA[kk][ty * 8 + 4];
            *(float4*)&b[0] = *(const float4*)&sB[kk][tx * 8];
            *(float4*)&b[4] = *(const float4*)&sB[kk][tx * 8 + 4];
#pragma unroll
            for (int i = 0; i < 8; ++i)
#pragma unroll
                for (int j = 0; j < 8; ++j) acc[i][j] = fmaf(a[i], b[j], acc[i][j]);
        }
        __syncthreads();
    }

    float bv[8];
#pragma unroll
    for (int j = 0; j < 8; ++j) bv[j] = bias ? bias[tx * 8 + j] : 0.f;

#pragma unroll
    for (int i = 0; i < 8; ++i) {
        int r = row0 + ty * 8 + i;
        if (r >= M) continue;
        float sc = scale ? scale[r] : 1.f;
        float* cp = C + (size_t)r * 128 + tx * 8;
        float4 o0, o1;
        o0.x = (acc[i][0] + bv[0]) * sc; o0.y = (acc[i][1] + bv[1]) * sc;
        o0.z = (acc[i][2] + bv[2]) * sc; o0.w = (acc[i][3] + bv[3]) * sc;
        o1.x = (acc[i][4] + bv[4]) * sc; o1.y = (acc[i][5] + bv[5]) * sc;
        o1.z = (acc[i][6] + bv[6]) * sc; o1.w = (acc[i][7] + bv[7]) * sc;
        *(float4*)cp = o0;
        *(float4*)(cp + 4) = o1;
    }
}

// ------------------------------------------------------------- aggregation
// zs is pre-scaled by norm[row]. out[i] = maybe_relu(norm[i]*(sum zs[src] + zs[i]) + b)
// one wave per node, float2 per lane over 128 cols, 8-deep pipelined gather.
__global__ __launch_bounds__(256) void agg_kernel(const float* __restrict__ zs,
                                                  const int* __restrict__ rowStart,
                                                  const int* __restrict__ colIdx,
                                                  const float* __restrict__ normv,
                                                  const float* __restrict__ bias,
                                                  float* __restrict__ out, int doRelu) {
    int wid = (blockIdx.x * 256 + threadIdx.x) >> 6;  // node id
    int lane = threadIdx.x & 63;
    if (wid >= N_NODES) return;
    int s0 = rowStart[wid];
    int s1 = rowStart[wid + 1];
    const int c = lane * 2;
    const float* zc = zs + c;

    float2 a0 = make_float2(0.f, 0.f), a1 = a0, a2 = a0, a3 = a0;
    int e = s0;
    for (; e + 8 <= s1; e += 8) {
        int i0 = colIdx[e + 0], i1 = colIdx[e + 1], i2 = colIdx[e + 2], i3 = colIdx[e + 3];
        int i4 = colIdx[e + 4], i5 = colIdx[e + 5], i6 = colIdx[e + 6], i7 = colIdx[e + 7];
        float2 v0 = *(const float2*)(zc + (size_t)i0 * 128);
        float2 v1 = *(const float2*)(zc + (size_t)i1 * 128);
        float2 v2 = *(const float2*)(zc + (size_t)i2 * 128);
        float2 v3 = *(const float2*)(zc + (size_t)i3 * 128);
        float2 v4 = *(const float2*)(zc + (size_t)i4 * 128);
        float2 v5 = *(const float2*)(zc + (size_t)i5 * 128);
        float2 v6 = *(const float2*)(zc + (size_t)i6 * 128);
        float2 v7 = *(const float2*)(zc + (size_t)i7 * 128);
        a0.x += v0.x + v4.x; a0.y += v0.y + v4.y;
        a1.x += v1.x + v5.x; a1.y += v1.y + v5.y;
        a2.x += v2.x + v6.x; a2.y += v2.y + v6.y;
        a3.x += v3.x + v7.x; a3.y += v3.y + v7.y;
    }
    if (e + 4 <= s1) {
        int i0 = colIdx[e + 0], i1 = colIdx[e + 1], i2 = colIdx[e + 2], i3 = colIdx[e + 3];
        float2 v0 = *(const float2*)(zc + (size_t)i0 * 128);
        float2 v1 = *(const float2*)(zc + (size_t)i1 * 128);
        float2 v2 = *(const float2*)(zc + (size_t)i2 * 128);
        float2 v3 = *(const float2*)(zc + (size_t)i3 * 128);
        a0.x += v0.x; a0.y += v0.y;
        a1.x += v1.x; a1.y += v1.y;
        a2.x += v2.x; a2.y += v2.y;
        a3.x += v3.x; a3.y += v3.y;
        e += 4;
    }
    for (; e < s1; ++e) {
        int i0 = colIdx[e];
        float2 v0 = *(const float2*)(zc + (size_t)i0 * 128);
        a0.x += v0.x; a0.y += v0.y;
    }

    float2 self = *(const float2*)(zc + (size_t)wid * 128);
    float sx = (a0.x + a1.x) + (a2.x + a3.x) + self.x;
    float sy = (a0.y + a1.y) + (a2.y + a3.y) + self.y;
    float nd = normv[wid];
    float2 bv = *(const float2*)(bias + c);
    float ox = fmaf(nd, sx, bv.x);
    float oy = fmaf(nd, sy, bv.y);
    if (doRelu) {
        ox = fmaxf(ox, 0.f);
        oy = fmaxf(oy, 0.f);
    }
    *(float2*)(out + (size_t)wid * 128 + c) = make_float2(ox, oy);
}

// ---------------------------------------------------------------- launcher
extern "C" void kernel_launch(void* const* d_in, const int* in_sizes, int n_in,
                              void* d_out, int out_size, void* d_ws, size_t ws_size,
                              hipStream_t stream) {
    const float* x  = (const float*)d_in[0];
    const int* ei   = (const int*)d_in[1];
    const float* Wp = (const float*)d_in[2];
    const float* bp = (const float*)d_in[3];
    const float* W1 = (const float*)d_in[4];
    const float* b1 = (const float*)d_in[5];
    const float* W2 = (const float*)d_in[6];
    const float* b2 = (const float*)d_in[7];
    float* out = (float*)d_out;

    const int* srcIdx = ei;             // edge_index[0]
    const int* dstIdx = ei + N_EDGES;   // edge_index[1]

    size_t off = 0;
    auto alloc = [&](size_t bytes) -> void* {
        void* p = (char*)d_ws + off;
        off += (bytes + 511) & ~(size_t)511;
        return p;
    };
    int* counts    = (int*)alloc((size_t)N_NODES * 4);
    int* rowStart  = (int*)alloc((size_t)(N_NODES + 1) * 4);
    int* cursor    = (int*)alloc((size_t)N_NODES * 4);
    int* colIdx    = (int*)alloc((size_t)N_EDGES * 4);
    int* chunkSums = (int*)alloc((size_t)NUM_CHUNKS * 4);
    int* chunkOff  = (int*)alloc((size_t)NUM_CHUNKS * 4);
    float* normv   = (float*)alloc((size_t)N_NODES * 4);
    float* Wc      = (float*)alloc((size_t)256 * 128 * 4);
    float* bc      = (float*)alloc((size_t)128 * 4);
    float* zA      = (float*)alloc((size_t)N_NODES * 128 * 4);
    float* zB      = (float*)alloc((size_t)N_NODES * 128 * 4);
    float* zC      = (float*)alloc((size_t)N_NODES * 128 * 4);

    const int EB = (N_EDGES + 255) / 256;       // 6250
    const int NBn = (N_NODES + 255) / 256;      // 391
    const int GB = (N_NODES + 127) / 128;       // 782
    const int AB = (N_NODES + 3) / 4;           // 25000

    // ---- CSR build ----
    hipMemsetAsync(counts, 0, (size_t)N_NODES * 4, stream);
    count_kernel<<<EB, 256, 0, stream>>>(dstIdx, counts);
    scan1_kernel<<<NUM_CHUNKS, 256, 0, stream>>>(counts, chunkSums);
    scan2_kernel<<<1, 1, 0, stream>>>(chunkSums, chunkOff, rowStart);
    scan3_kernel<<<NUM_CHUNKS, 256, 0, stream>>>(counts, chunkOff, rowStart);
    norm_kernel<<<NBn, 256, 0, stream>>>(counts, normv);
    hipMemcpyAsync(cursor, rowStart, (size_t)N_NODES * 4, hipMemcpyDeviceToDevice, stream);
    fill_kernel<<<EB, 256, 0, stream>>>(srcIdx, dstIdx, cursor, colIdx);

    // ---- collapsed weights: Wc = Wp@W1, bc = bp@W1 ----
    wc_kernel<<<257, 128, 0, stream>>>(Wp, bp, W1, Wc, bc);

    // ---- pipeline ----
    // zA = (x @ Wc + bc) * norm[row]      (z1 pre-scaled)
    gemm_kernel<<<GB, 256, 0, stream>>>(x, Wc, bc, normv, zA, N_NODES, 256);
    // zB = relu(norm*(sum zA[src] + zA[self]) + b1)
    agg_kernel<<<AB, 256, 0, stream>>>(zA, rowStart, colIdx, normv, b1, zB, 1);
    // zC = (zB @ W2) * norm[row]
    gemm_kernel<<<GB, 256, 0, stream>>>(zB, W2, nullptr, normv, zC, N_NODES, 128);
    // out = norm*(sum zC[src] + zC[self]) + b2
    agg_kernel<<<AB, 256, 0, stream>>>(zC, rowStart, colIdx, normv, b2, out, 0);
}

// Round 4
// 595.365 us; speedup vs baseline: 1.5039x; 1.2484x over previous
//
#include <hip/hip_runtime.h>
#include <cstdint>
#include <cstddef>

#define N_NODES 100000
#define N_EDGES 1600000

// ---- bucketed counting-sort CSR parameters ----
constexpr int NPB = 512;                               // nodes per bucket (2^9)
constexpr int NBUCK = (N_NODES + NPB - 1) / NPB;       // 196
constexpr int EPB = 8192;                              // edges per block in B1/B2
constexpr int NCHUNK = (N_EDGES + EPB - 1) / EPB;      // 196

typedef _Float16 half8 __attribute__((ext_vector_type(8)));
typedef _Float16 half4v __attribute__((ext_vector_type(4)));
typedef float f32x4 __attribute__((ext_vector_type(4)));

// ================================================================= CSR build
// B1: per-(bucket, block) edge histogram
__global__ __launch_bounds__(256) void b1_hist(const int* __restrict__ dst,
                                               int* __restrict__ bbc) {
    __shared__ int hist[NBUCK];
    int t = threadIdx.x;
    if (t < NBUCK) hist[t] = 0;
    __syncthreads();
    int base = blockIdx.x * EPB;
#pragma unroll
    for (int i = 0; i < EPB / 256; ++i) {
        int e = base + i * 256 + t;
        if (e < N_EDGES) atomicAdd(&hist[dst[e] >> 9], 1);
    }
    __syncthreads();
    if (t < NBUCK) bbc[t * NCHUNK + blockIdx.x] = hist[t];
}

// scan: per-bucket exclusive over blocks (in place) + bucket offsets
__global__ void b_scan(int* __restrict__ bbc, int* __restrict__ bucketOff,
                       int* __restrict__ rowStart) {
    __shared__ int tot[NBUCK];
    int t = threadIdx.x;
    if (t < NBUCK) {
        int run = 0;
        for (int blk = 0; blk < NCHUNK; ++blk) {
            int idx = t * NCHUNK + blk;
            int c = bbc[idx];
            bbc[idx] = run;
            run += c;
        }
        tot[t] = run;
    }
    __syncthreads();
    if (t == 0) {
        int acc = 0;
        for (int b = 0; b < NBUCK; ++b) {
            bucketOff[b] = acc;
            acc += tot[b];
        }
        bucketOff[NBUCK] = acc;        // == N_EDGES
        rowStart[N_NODES] = acc;
    }
}

// B2: scatter packed (dstLocal<<17 | src) into bucket-ordered staging
__global__ __launch_bounds__(256) void b2_scatter(const int* __restrict__ src,
                                                  const int* __restrict__ dst,
                                                  const int* __restrict__ bbc,
                                                  const int* __restrict__ bucketOff,
                                                  int* __restrict__ staged) {
    __shared__ int cnt[NBUCK];
    __shared__ int base[NBUCK];
    int t = threadIdx.x;
    if (t < NBUCK) {
        cnt[t] = 0;
        base[t] = bucketOff[t] + bbc[t * NCHUNK + blockIdx.x];
    }
    __syncthreads();
    int ebase = blockIdx.x * EPB;
#pragma unroll
    for (int i = 0; i < EPB / 256; ++i) {
        int e = ebase + i * 256 + t;
        if (e < N_EDGES) {
            int d = dst[e];
            int b = d >> 9;
            int r = atomicAdd(&cnt[b], 1);
            staged[base[b] + r] = ((d & 511) << 17) | src[e];
        }
    }
}

// B3: per-bucket local counting sort -> rowStart, normv, colIdx
__global__ __launch_bounds__(256) void b3_sort(const int* __restrict__ staged,
                                               const int* __restrict__ bucketOff,
                                               int* __restrict__ rowStart,
                                               float* __restrict__ normv,
                                               int* __restrict__ colIdx) {
    __shared__ int hist[NPB];
    __shared__ int sc0[NPB], sc1[NPB];
    __shared__ int cursor[NPB];
    int t = threadIdx.x;
    int b = blockIdx.x;
    int e0 = bucketOff[b], e1 = bucketOff[b + 1];
    int ne = e1 - e0;
    int node0 = b * NPB;
    int nn = min(NPB, N_NODES - node0);

    for (int j = t; j < NPB; j += 256) hist[j] = 0;
    __syncthreads();
    for (int idx = t; idx < ne; idx += 256)
        atomicAdd(&hist[staged[e0 + idx] >> 17], 1);
    __syncthreads();
    for (int j = t; j < NPB; j += 256) sc0[j] = hist[j];
    __syncthreads();
    // Hillis-Steele inclusive scan over 512
    int* s = sc0;
    int* d = sc1;
    for (int off = 1; off < NPB; off <<= 1) {
        for (int j = t; j < NPB; j += 256) d[j] = s[j] + (j >= off ? s[j - off] : 0);
        __syncthreads();
        int* tmp = s; s = d; d = tmp;
    }
    // s = inclusive scan; excl = s[j]-hist[j]
    for (int j = t; j < NPB; j += 256) {
        int excl = s[j] - hist[j];
        cursor[j] = excl;
        if (j < nn) {
            rowStart[node0 + j] = e0 + excl;
            normv[node0 + j] = (float)(1.0 / sqrt((double)(hist[j] + 1)));
        }
    }
    __syncthreads();
    for (int idx = t; idx < ne; idx += 256) {
        int v = staged[e0 + idx];
        int dl = v >> 17;
        int sn = v & 0x1FFFF;
        int r = atomicAdd(&cursor[dl], 1);
        colIdx[e0 + r] = sn;
    }
}

// ================================================== weight prep (tiny)
// Wc = Wp@W1 (fp32), bc = bp@W1
__global__ void wc_kernel(const float* __restrict__ Wp, const float* __restrict__ bp,
                          const float* __restrict__ W1, float* __restrict__ Wc,
                          float* __restrict__ bc) {
    int r = blockIdx.x;
    int cc = threadIdx.x;
    float acc = 0.f;
    if (r < 256) {
        for (int k = 0; k < 128; ++k) acc = fmaf(Wp[r * 128 + k], W1[k * 128 + cc], acc);
        Wc[r * 128 + cc] = acc;
    } else {
        for (int k = 0; k < 128; ++k) acc = fmaf(bp[k], W1[k * 128 + cc], acc);
        bc[cc] = acc;
    }
}

// transpose + f16 hi/lo split: W[K][128] -> Oh/Ol[128][K]
__global__ void tsplit_kernel(const float* __restrict__ W, _Float16* __restrict__ Oh,
                              _Float16* __restrict__ Ol, int K) {
    int id = blockIdx.x * 256 + threadIdx.x;
    if (id >= K * 128) return;
    int n = id / K;
    int k = id - n * K;
    float v = W[k * 128 + n];
    _Float16 h = (_Float16)v;
    Oh[id] = h;
    Ol[id] = (_Float16)(v - (float)h);
}

// =============================================== split-f16 MFMA GEMM
// C[r][c] = (sum_k A[r][k]*B[k][c] + bias[c]) * scale[r]
// A fp32 [M][K] split on the fly; B pre-split transposed f16 [128][K].
// BM=128 rows/block, N=128 full, BK=32. 256 thr = 4 waves; wave w: rows [32w,32w+32).
__global__ __launch_bounds__(256) void mfma_gemm(const float* __restrict__ A,
                                                 const _Float16* __restrict__ Bth,
                                                 const _Float16* __restrict__ Btl,
                                                 const float* __restrict__ bias,
                                                 const float* __restrict__ scale,
                                                 float* __restrict__ C, int M, int K) {
    __shared__ _Float16 sAh[128 * 40];
    __shared__ _Float16 sAl[128 * 40];
    __shared__ _Float16 sBh[128 * 40];
    __shared__ _Float16 sBl[128 * 40];
    const int t = threadIdx.x;
    const int w = t >> 6;
    const int lane = t & 63;
    const int q = lane >> 4;       // quad 0..3
    const int mr = lane & 15;
    const int row0 = blockIdx.x * 128;

    f32x4 acc[2][8];
#pragma unroll
    for (int mt = 0; mt < 2; ++mt)
#pragma unroll
        for (int nt = 0; nt < 8; ++nt) acc[mt][nt] = (f32x4){0.f, 0.f, 0.f, 0.f};

    for (int k0 = 0; k0 < K; k0 += 32) {
        // stage A 128x32 fp32 -> hi/lo f16 (row stride 40 f16)
#pragma unroll
        for (int i = 0; i < 4; ++i) {
            int id = t + i * 256;
            int r = id >> 3;
            int c4 = (id & 7) * 4;
            float4 v = make_float4(0.f, 0.f, 0.f, 0.f);
            if (row0 + r < M) v = *(const float4*)(A + (size_t)(row0 + r) * K + k0 + c4);
            half4v hh, ll;
            hh[0] = (_Float16)v.x; ll[0] = (_Float16)(v.x - (float)hh[0]);
            hh[1] = (_Float16)v.y; ll[1] = (_Float16)(v.y - (float)hh[1]);
            hh[2] = (_Float16)v.z; ll[2] = (_Float16)(v.z - (float)hh[2]);
            hh[3] = (_Float16)v.w; ll[3] = (_Float16)(v.w - (float)hh[3]);
            *(half4v*)&sAh[r * 40 + c4] = hh;
            *(half4v*)&sAl[r * 40 + c4] = ll;
        }
        // stage B tiles (already split, transposed [n][K])
#pragma unroll
        for (int i = 0; i < 2; ++i) {
            int id = t + i * 256;
            int n = id >> 2;
            int c8 = (id & 3) * 8;
            *(half8*)&sBh[n * 40 + c8] = *(const half8*)(Bth + (size_t)n * K + k0 + c8);
            *(half8*)&sBl[n * 40 + c8] = *(const half8*)(Btl + (size_t)n * K + k0 + c8);
        }
        __syncthreads();

        half8 ah[2], al[2], bh[8], bl[8];
#pragma unroll
        for (int mt = 0; mt < 2; ++mt) {
            int m = w * 32 + mt * 16 + mr;
            ah[mt] = *(half8*)&sAh[m * 40 + q * 8];
            al[mt] = *(half8*)&sAl[m * 40 + q * 8];
        }
#pragma unroll
        for (int nt = 0; nt < 8; ++nt) {
            int n = nt * 16 + mr;
            bh[nt] = *(half8*)&sBh[n * 40 + q * 8];
            bl[nt] = *(half8*)&sBl[n * 40 + q * 8];
        }
#pragma unroll
        for (int mt = 0; mt < 2; ++mt)
#pragma unroll
            for (int nt = 0; nt < 8; ++nt) {
                acc[mt][nt] = __builtin_amdgcn_mfma_f32_16x16x32_f16(ah[mt], bh[nt], acc[mt][nt], 0, 0, 0);
                acc[mt][nt] = __builtin_amdgcn_mfma_f32_16x16x32_f16(ah[mt], bl[nt], acc[mt][nt], 0, 0, 0);
                acc[mt][nt] = __builtin_amdgcn_mfma_f32_16x16x32_f16(al[mt], bh[nt], acc[mt][nt], 0, 0, 0);
            }
        __syncthreads();
    }

    // epilogue: C/D layout col=lane&15, row=quad*4+reg
#pragma unroll
    for (int mt = 0; mt < 2; ++mt) {
#pragma unroll
        for (int r = 0; r < 4; ++r) {
            int row = row0 + w * 32 + mt * 16 + q * 4 + r;
            if (row >= M) continue;
            float sc = scale[row];
#pragma unroll
            for (int nt = 0; nt < 8; ++nt) {
                int col = nt * 16 + mr;
                float bv = bias ? bias[col] : 0.f;
                C[(size_t)row * 128 + col] = (acc[mt][nt][r] + bv) * sc;
            }
        }
    }
}

// ------------------------------------------------------------- aggregation
// zs pre-scaled by norm[row]. out[i] = maybe_relu(norm[i]*(sum zs[src] + zs[i]) + b)
__global__ __launch_bounds__(256) void agg_kernel(const float* __restrict__ zs,
                                                  const int* __restrict__ rowStart,
                                                  const int* __restrict__ colIdx,
                                                  const float* __restrict__ normv,
                                                  const float* __restrict__ bias,
                                                  float* __restrict__ out, int doRelu) {
    int wid = (blockIdx.x * 256 + threadIdx.x) >> 6;
    int lane = threadIdx.x & 63;
    if (wid >= N_NODES) return;
    int s0 = rowStart[wid];
    int s1 = rowStart[wid + 1];
    const int c = lane * 2;
    const float* zc = zs + c;

    float2 a0 = make_float2(0.f, 0.f), a1 = a0, a2 = a0, a3 = a0;
    int e = s0;
    for (; e + 8 <= s1; e += 8) {
        int i0 = colIdx[e + 0], i1 = colIdx[e + 1], i2 = colIdx[e + 2], i3 = colIdx[e + 3];
        int i4 = colIdx[e + 4], i5 = colIdx[e + 5], i6 = colIdx[e + 6], i7 = colIdx[e + 7];
        float2 v0 = *(const float2*)(zc + (size_t)i0 * 128);
        float2 v1 = *(const float2*)(zc + (size_t)i1 * 128);
        float2 v2 = *(const float2*)(zc + (size_t)i2 * 128);
        float2 v3 = *(const float2*)(zc + (size_t)i3 * 128);
        float2 v4 = *(const float2*)(zc + (size_t)i4 * 128);
        float2 v5 = *(const float2*)(zc + (size_t)i5 * 128);
        float2 v6 = *(const float2*)(zc + (size_t)i6 * 128);
        float2 v7 = *(const float2*)(zc + (size_t)i7 * 128);
        a0.x += v0.x + v4.x; a0.y += v0.y + v4.y;
        a1.x += v1.x + v5.x; a1.y += v1.y + v5.y;
        a2.x += v2.x + v6.x; a2.y += v2.y + v6.y;
        a3.x += v3.x + v7.x; a3.y += v3.y + v7.y;
    }
    if (e + 4 <= s1) {
        int i0 = colIdx[e + 0], i1 = colIdx[e + 1], i2 = colIdx[e + 2], i3 = colIdx[e + 3];
        float2 v0 = *(const float2*)(zc + (size_t)i0 * 128);
        float2 v1 = *(const float2*)(zc + (size_t)i1 * 128);
        float2 v2 = *(const float2*)(zc + (size_t)i2 * 128);
        float2 v3 = *(const float2*)(zc + (size_t)i3 * 128);
        a0.x += v0.x; a0.y += v0.y;
        a1.x += v1.x; a1.y += v1.y;
        a2.x += v2.x; a2.y += v2.y;
        a3.x += v3.x; a3.y += v3.y;
        e += 4;
    }
    for (; e < s1; ++e) {
        int i0 = colIdx[e];
        float2 v0 = *(const float2*)(zc + (size_t)i0 * 128);
        a0.x += v0.x; a0.y += v0.y;
    }

    float2 self = *(const float2*)(zc + (size_t)wid * 128);
    float sx = (a0.x + a1.x) + (a2.x + a3.x) + self.x;
    float sy = (a0.y + a1.y) + (a2.y + a3.y) + self.y;
    float nd = normv[wid];
    float2 bv = *(const float2*)(bias + c);
    float ox = fmaf(nd, sx, bv.x);
    float oy = fmaf(nd, sy, bv.y);
    if (doRelu) {
        ox = fmaxf(ox, 0.f);
        oy = fmaxf(oy, 0.f);
    }
    *(float2*)(out + (size_t)wid * 128 + c) = make_float2(ox, oy);
}

// ---------------------------------------------------------------- launcher
extern "C" void kernel_launch(void* const* d_in, const int* in_sizes, int n_in,
                              void* d_out, int out_size, void* d_ws, size_t ws_size,
                              hipStream_t stream) {
    const float* x  = (const float*)d_in[0];
    const int* ei   = (const int*)d_in[1];
    const float* Wp = (const float*)d_in[2];
    const float* bp = (const float*)d_in[3];
    const float* W1 = (const float*)d_in[4];
    const float* b1 = (const float*)d_in[5];
    const float* W2 = (const float*)d_in[6];
    const float* b2 = (const float*)d_in[7];
    float* out = (float*)d_out;

    const int* srcIdx = ei;
    const int* dstIdx = ei + N_EDGES;

    size_t off = 0;
    auto alloc = [&](size_t bytes) -> void* {
        void* p = (char*)d_ws + off;
        off += (bytes + 511) & ~(size_t)511;
        return p;
    };
    int* rowStart   = (int*)alloc((size_t)(N_NODES + 1) * 4);
    int* colIdx     = (int*)alloc((size_t)N_EDGES * 4);
    int* staged     = (int*)alloc((size_t)N_EDGES * 4);
    int* bbc        = (int*)alloc((size_t)NBUCK * NCHUNK * 4);
    int* bucketOff  = (int*)alloc((size_t)(NBUCK + 1) * 4);
    float* normv    = (float*)alloc((size_t)N_NODES * 4);
    float* Wc       = (float*)alloc((size_t)256 * 128 * 4);
    float* bc       = (float*)alloc((size_t)128 * 4);
    _Float16* Wcth  = (_Float16*)alloc((size_t)128 * 256 * 2);
    _Float16* Wctl  = (_Float16*)alloc((size_t)128 * 256 * 2);
    _Float16* W2th  = (_Float16*)alloc((size_t)128 * 128 * 2);
    _Float16* W2tl  = (_Float16*)alloc((size_t)128 * 128 * 2);
    float* zA       = (float*)alloc((size_t)N_NODES * 128 * 4);
    float* zB       = (float*)alloc((size_t)N_NODES * 128 * 4);

    const int GB = (N_NODES + 127) / 128;  // 782
    const int AB = (N_NODES + 3) / 4;      // 25000

    // ---- CSR build (bucketed counting sort) ----
    b1_hist<<<NCHUNK, 256, 0, stream>>>(dstIdx, bbc);
    b_scan<<<1, 256, 0, stream>>>(bbc, bucketOff, rowStart);
    b2_scatter<<<NCHUNK, 256, 0, stream>>>(srcIdx, dstIdx, bbc, bucketOff, staged);
    b3_sort<<<NBUCK, 256, 0, stream>>>(staged, bucketOff, rowStart, normv, colIdx);

    // ---- weight prep ----
    wc_kernel<<<257, 128, 0, stream>>>(Wp, bp, W1, Wc, bc);
    tsplit_kernel<<<(256 * 128 + 255) / 256, 256, 0, stream>>>(Wc, Wcth, Wctl, 256);
    tsplit_kernel<<<(128 * 128 + 255) / 256, 256, 0, stream>>>(W2, W2th, W2tl, 128);

    // ---- pipeline ----
    // zA = (x @ Wc + bc) * norm[row]
    mfma_gemm<<<GB, 256, 0, stream>>>(x, Wcth, Wctl, bc, normv, zA, N_NODES, 256);
    // zB = relu(norm*(sum zA[src] + zA[self]) + b1)
    agg_kernel<<<AB, 256, 0, stream>>>(zA, rowStart, colIdx, normv, b1, zB, 1);
    // zA (reused) = (zB @ W2) * norm[row]
    mfma_gemm<<<GB, 256, 0, stream>>>(zB, W2th, W2tl, nullptr, normv, zA, N_NODES, 128);
    // out = norm*(sum zA[src] + zA[self]) + b2
    agg_kernel<<<AB, 256, 0, stream>>>(zA, rowStart, colIdx, normv, b2, out, 0);
}

// Round 5
// 483.930 us; speedup vs baseline: 1.8502x; 1.2303x over previous
//
#include <hip/hip_runtime.h>
#include <cstdint>
#include <cstddef>

#define N_NODES 100000
#define N_EDGES 1600000

// ---- bucketed counting-sort CSR parameters ----
constexpr int NPB = 512;                               // nodes per bucket (2^9)
constexpr int NBUCK = (N_NODES + NPB - 1) / NPB;       // 196
constexpr int EPB = 8192;                              // edges per block in B1/B2
constexpr int NCHUNK = (N_EDGES + EPB - 1) / EPB;      // 196

typedef _Float16 half8 __attribute__((ext_vector_type(8)));
typedef _Float16 half4v __attribute__((ext_vector_type(4)));
typedef _Float16 half2v __attribute__((ext_vector_type(2)));
typedef float f32x4 __attribute__((ext_vector_type(4)));

// ================================================================= CSR build
__global__ __launch_bounds__(256) void b1_hist(const int* __restrict__ dst,
                                               int* __restrict__ bbc) {
    __shared__ int hist[NBUCK];
    int t = threadIdx.x;
    if (t < NBUCK) hist[t] = 0;
    __syncthreads();
    int base = blockIdx.x * EPB;
#pragma unroll
    for (int i = 0; i < EPB / 256; ++i) {
        int e = base + i * 256 + t;
        if (e < N_EDGES) atomicAdd(&hist[dst[e] >> 9], 1);
    }
    __syncthreads();
    if (t < NBUCK) bbc[t * NCHUNK + blockIdx.x] = hist[t];
}

__global__ void b_scan(int* __restrict__ bbc, int* __restrict__ bucketOff,
                       int* __restrict__ rowStart) {
    __shared__ int tot[NBUCK];
    int t = threadIdx.x;
    if (t < NBUCK) {
        int run = 0;
        for (int blk = 0; blk < NCHUNK; ++blk) {
            int idx = t * NCHUNK + blk;
            int c = bbc[idx];
            bbc[idx] = run;
            run += c;
        }
        tot[t] = run;
    }
    __syncthreads();
    if (t == 0) {
        int acc = 0;
        for (int b = 0; b < NBUCK; ++b) {
            bucketOff[b] = acc;
            acc += tot[b];
        }
        bucketOff[NBUCK] = acc;
        rowStart[N_NODES] = acc;
    }
}

__global__ __launch_bounds__(256) void b2_scatter(const int* __restrict__ src,
                                                  const int* __restrict__ dst,
                                                  const int* __restrict__ bbc,
                                                  const int* __restrict__ bucketOff,
                                                  int* __restrict__ staged) {
    __shared__ int cnt[NBUCK];
    __shared__ int base[NBUCK];
    int t = threadIdx.x;
    if (t < NBUCK) {
        cnt[t] = 0;
        base[t] = bucketOff[t] + bbc[t * NCHUNK + blockIdx.x];
    }
    __syncthreads();
    int ebase = blockIdx.x * EPB;
#pragma unroll
    for (int i = 0; i < EPB / 256; ++i) {
        int e = ebase + i * 256 + t;
        if (e < N_EDGES) {
            int d = dst[e];
            int b = d >> 9;
            int r = atomicAdd(&cnt[b], 1);
            staged[base[b] + r] = ((d & 511) << 17) | src[e];
        }
    }
}

__global__ __launch_bounds__(256) void b3_sort(const int* __restrict__ staged,
                                               const int* __restrict__ bucketOff,
                                               int* __restrict__ rowStart,
                                               float* __restrict__ normv,
                                               int* __restrict__ colIdx) {
    __shared__ int hist[NPB];
    __shared__ int sc0[NPB], sc1[NPB];
    __shared__ int cursor[NPB];
    int t = threadIdx.x;
    int b = blockIdx.x;
    int e0 = bucketOff[b], e1 = bucketOff[b + 1];
    int ne = e1 - e0;
    int node0 = b * NPB;
    int nn = min(NPB, N_NODES - node0);

    for (int j = t; j < NPB; j += 256) hist[j] = 0;
    __syncthreads();
    for (int idx = t; idx < ne; idx += 256)
        atomicAdd(&hist[staged[e0 + idx] >> 17], 1);
    __syncthreads();
    for (int j = t; j < NPB; j += 256) sc0[j] = hist[j];
    __syncthreads();
    int* s = sc0;
    int* d = sc1;
    for (int off = 1; off < NPB; off <<= 1) {
        for (int j = t; j < NPB; j += 256) d[j] = s[j] + (j >= off ? s[j - off] : 0);
        __syncthreads();
        int* tmp = s; s = d; d = tmp;
    }
    for (int j = t; j < NPB; j += 256) {
        int excl = s[j] - hist[j];
        cursor[j] = excl;
        if (j < nn) {
            rowStart[node0 + j] = e0 + excl;
            normv[node0 + j] = (float)(1.0 / sqrt((double)(hist[j] + 1)));
        }
    }
    __syncthreads();
    for (int idx = t; idx < ne; idx += 256) {
        int v = staged[e0 + idx];
        int dl = v >> 17;
        int sn = v & 0x1FFFF;
        int r = atomicAdd(&cursor[dl], 1);
        colIdx[e0 + r] = sn;
    }
}

// ================================================== weight prep (tiny)
__global__ void wc_kernel(const float* __restrict__ Wp, const float* __restrict__ bp,
                          const float* __restrict__ W1, float* __restrict__ Wc,
                          float* __restrict__ bc) {
    int r = blockIdx.x;
    int cc = threadIdx.x;
    float acc = 0.f;
    if (r < 256) {
        for (int k = 0; k < 128; ++k) acc = fmaf(Wp[r * 128 + k], W1[k * 128 + cc], acc);
        Wc[r * 128 + cc] = acc;
    } else {
        for (int k = 0; k < 128; ++k) acc = fmaf(bp[k], W1[k * 128 + cc], acc);
        bc[cc] = acc;
    }
}

// transpose + f16 hi/lo split: W[K][128] -> Oh/Ol[128][K]
__global__ void tsplit_kernel(const float* __restrict__ W, _Float16* __restrict__ Oh,
                              _Float16* __restrict__ Ol, int K) {
    int id = blockIdx.x * 256 + threadIdx.x;
    if (id >= K * 128) return;
    int n = id / K;
    int k = id - n * K;
    float v = W[k * 128 + n];
    _Float16 h = (_Float16)v;
    Oh[id] = h;
    Ol[id] = (_Float16)(v - (float)h);
}

// =============================================== split-f16 MFMA GEMM
// C[r][c] = (sum_k A[r][k]*B[k][c] + bias[c]) * scale[r], C stored fp16 or fp32.
// AF16=false: A fp32, split on the fly, 3 MFMA products.
// AF16=true:  A fp16 native, 2 MFMA products (A exact).
template <bool AF16>
__global__ __launch_bounds__(256) void mfma_gemm(const float* __restrict__ Af,
                                                 const _Float16* __restrict__ Ah,
                                                 const _Float16* __restrict__ Bth,
                                                 const _Float16* __restrict__ Btl,
                                                 const float* __restrict__ bias,
                                                 const float* __restrict__ scale,
                                                 float* __restrict__ Cf,
                                                 _Float16* __restrict__ Ch,
                                                 int M, int K) {
    __shared__ _Float16 sAh[128 * 40];
    __shared__ _Float16 sAl[AF16 ? 8 : 128 * 40];
    __shared__ _Float16 sBh[128 * 40];
    __shared__ _Float16 sBl[128 * 40];
    const int t = threadIdx.x;
    const int w = t >> 6;
    const int lane = t & 63;
    const int q = lane >> 4;
    const int mr = lane & 15;
    const int row0 = blockIdx.x * 128;

    f32x4 acc[2][8];
#pragma unroll
    for (int mt = 0; mt < 2; ++mt)
#pragma unroll
        for (int nt = 0; nt < 8; ++nt) acc[mt][nt] = (f32x4){0.f, 0.f, 0.f, 0.f};

    for (int k0 = 0; k0 < K; k0 += 32) {
        if constexpr (AF16) {
            // stage A 128x32 f16 directly: 2 iters x 256 thr x 8 halves
#pragma unroll
            for (int i = 0; i < 2; ++i) {
                int id = t + i * 256;
                int r = id >> 2;
                int c8 = (id & 3) * 8;
                half8 v = {0, 0, 0, 0, 0, 0, 0, 0};
                if (row0 + r < M) v = *(const half8*)(Ah + (size_t)(row0 + r) * K + k0 + c8);
                *(half8*)&sAh[r * 40 + c8] = v;
            }
        } else {
            // stage A 128x32 fp32 -> hi/lo f16
#pragma unroll
            for (int i = 0; i < 4; ++i) {
                int id = t + i * 256;
                int r = id >> 3;
                int c4 = (id & 7) * 4;
                float4 v = make_float4(0.f, 0.f, 0.f, 0.f);
                if (row0 + r < M) v = *(const float4*)(Af + (size_t)(row0 + r) * K + k0 + c4);
                half4v hh, ll;
                hh[0] = (_Float16)v.x; ll[0] = (_Float16)(v.x - (float)hh[0]);
                hh[1] = (_Float16)v.y; ll[1] = (_Float16)(v.y - (float)hh[1]);
                hh[2] = (_Float16)v.z; ll[2] = (_Float16)(v.z - (float)hh[2]);
                hh[3] = (_Float16)v.w; ll[3] = (_Float16)(v.w - (float)hh[3]);
                *(half4v*)&sAh[r * 40 + c4] = hh;
                *(half4v*)&sAl[r * 40 + c4] = ll;
            }
        }
        // stage B tiles (pre-split, transposed [n][K])
#pragma unroll
        for (int i = 0; i < 2; ++i) {
            int id = t + i * 256;
            int n = id >> 2;
            int c8 = (id & 3) * 8;
            *(half8*)&sBh[n * 40 + c8] = *(const half8*)(Bth + (size_t)n * K + k0 + c8);
            *(half8*)&sBl[n * 40 + c8] = *(const half8*)(Btl + (size_t)n * K + k0 + c8);
        }
        __syncthreads();

        half8 ah[2], al[2], bh[8], bl[8];
#pragma unroll
        for (int mt = 0; mt < 2; ++mt) {
            int m = w * 32 + mt * 16 + mr;
            ah[mt] = *(half8*)&sAh[m * 40 + q * 8];
            if constexpr (!AF16) al[mt] = *(half8*)&sAl[m * 40 + q * 8];
        }
#pragma unroll
        for (int nt = 0; nt < 8; ++nt) {
            int n = nt * 16 + mr;
            bh[nt] = *(half8*)&sBh[n * 40 + q * 8];
            bl[nt] = *(half8*)&sBl[n * 40 + q * 8];
        }
#pragma unroll
        for (int mt = 0; mt < 2; ++mt)
#pragma unroll
            for (int nt = 0; nt < 8; ++nt) {
                acc[mt][nt] = __builtin_amdgcn_mfma_f32_16x16x32_f16(ah[mt], bh[nt], acc[mt][nt], 0, 0, 0);
                acc[mt][nt] = __builtin_amdgcn_mfma_f32_16x16x32_f16(ah[mt], bl[nt], acc[mt][nt], 0, 0, 0);
                if constexpr (!AF16)
                    acc[mt][nt] = __builtin_amdgcn_mfma_f32_16x16x32_f16(al[mt], bh[nt], acc[mt][nt], 0, 0, 0);
            }
        __syncthreads();
    }

    // epilogue: C/D layout col=lane&15, row=quad*4+reg
#pragma unroll
    for (int mt = 0; mt < 2; ++mt) {
#pragma unroll
        for (int r = 0; r < 4; ++r) {
            int row = row0 + w * 32 + mt * 16 + q * 4 + r;
            if (row >= M) continue;
            float sc = scale[row];
#pragma unroll
            for (int nt = 0; nt < 8; ++nt) {
                int col = nt * 16 + mr;
                float bv = bias ? bias[col] : 0.f;
                float val = (acc[mt][nt][r] + bv) * sc;
                if (Ch) Ch[(size_t)row * 128 + col] = (_Float16)val;
                else    Cf[(size_t)row * 128 + col] = val;
            }
        }
    }
}

// ------------------------------------------------------------- aggregation
// zs fp16 pre-scaled by norm[row]. out = maybe_relu(norm[i]*(sum zs[src]+zs[i])+b)
// one wave per node, 1 dword (2 halves) per lane, fp32 accumulate.
__global__ __launch_bounds__(256) void agg_kernel(const _Float16* __restrict__ zs,
                                                  const int* __restrict__ rowStart,
                                                  const int* __restrict__ colIdx,
                                                  const float* __restrict__ normv,
                                                  const float* __restrict__ bias,
                                                  float* __restrict__ outF,
                                                  _Float16* __restrict__ outH,
                                                  int doRelu) {
    int wid = (blockIdx.x * 256 + threadIdx.x) >> 6;
    int lane = threadIdx.x & 63;
    if (wid >= N_NODES) return;
    int s0 = rowStart[wid];
    int s1 = rowStart[wid + 1];
    const int c = lane * 2;
    const _Float16* zc = zs + c;

    float2 a0 = make_float2(0.f, 0.f), a1 = a0, a2 = a0, a3 = a0;
    int e = s0;
    for (; e + 8 <= s1; e += 8) {
        int i0 = colIdx[e + 0], i1 = colIdx[e + 1], i2 = colIdx[e + 2], i3 = colIdx[e + 3];
        int i4 = colIdx[e + 4], i5 = colIdx[e + 5], i6 = colIdx[e + 6], i7 = colIdx[e + 7];
        half2v v0 = *(const half2v*)(zc + (size_t)i0 * 128);
        half2v v1 = *(const half2v*)(zc + (size_t)i1 * 128);
        half2v v2 = *(const half2v*)(zc + (size_t)i2 * 128);
        half2v v3 = *(const half2v*)(zc + (size_t)i3 * 128);
        half2v v4 = *(const half2v*)(zc + (size_t)i4 * 128);
        half2v v5 = *(const half2v*)(zc + (size_t)i5 * 128);
        half2v v6 = *(const half2v*)(zc + (size_t)i6 * 128);
        half2v v7 = *(const half2v*)(zc + (size_t)i7 * 128);
        a0.x += (float)v0[0] + (float)v4[0]; a0.y += (float)v0[1] + (float)v4[1];
        a1.x += (float)v1[0] + (float)v5[0]; a1.y += (float)v1[1] + (float)v5[1];
        a2.x += (float)v2[0] + (float)v6[0]; a2.y += (float)v2[1] + (float)v6[1];
        a3.x += (float)v3[0] + (float)v7[0]; a3.y += (float)v3[1] + (float)v7[1];
    }
    if (e + 4 <= s1) {
        int i0 = colIdx[e + 0], i1 = colIdx[e + 1], i2 = colIdx[e + 2], i3 = colIdx[e + 3];
        half2v v0 = *(const half2v*)(zc + (size_t)i0 * 128);
        half2v v1 = *(const half2v*)(zc + (size_t)i1 * 128);
        half2v v2 = *(const half2v*)(zc + (size_t)i2 * 128);
        half2v v3 = *(const half2v*)(zc + (size_t)i3 * 128);
        a0.x += (float)v0[0]; a0.y += (float)v0[1];
        a1.x += (float)v1[0]; a1.y += (float)v1[1];
        a2.x += (float)v2[0]; a2.y += (float)v2[1];
        a3.x += (float)v3[0]; a3.y += (float)v3[1];
        e += 4;
    }
    for (; e < s1; ++e) {
        int i0 = colIdx[e];
        half2v v0 = *(const half2v*)(zc + (size_t)i0 * 128);
        a0.x += (float)v0[0]; a0.y += (float)v0[1];
    }

    half2v self = *(const half2v*)(zc + (size_t)wid * 128);
    float sx = (a0.x + a1.x) + (a2.x + a3.x) + (float)self[0];
    float sy = (a0.y + a1.y) + (a2.y + a3.y) + (float)self[1];
    float nd = normv[wid];
    float2 bv = *(const float2*)(bias + c);
    float ox = fmaf(nd, sx, bv.x);
    float oy = fmaf(nd, sy, bv.y);
    if (doRelu) {
        ox = fmaxf(ox, 0.f);
        oy = fmaxf(oy, 0.f);
    }
    if (outH) {
        half2v o;
        o[0] = (_Float16)ox;
        o[1] = (_Float16)oy;
        *(half2v*)(outH + (size_t)wid * 128 + c) = o;
    } else {
        *(float2*)(outF + (size_t)wid * 128 + c) = make_float2(ox, oy);
    }
}

// ---------------------------------------------------------------- launcher
extern "C" void kernel_launch(void* const* d_in, const int* in_sizes, int n_in,
                              void* d_out, int out_size, void* d_ws, size_t ws_size,
                              hipStream_t stream) {
    const float* x  = (const float*)d_in[0];
    const int* ei   = (const int*)d_in[1];
    const float* Wp = (const float*)d_in[2];
    const float* bp = (const float*)d_in[3];
    const float* W1 = (const float*)d_in[4];
    const float* b1 = (const float*)d_in[5];
    const float* W2 = (const float*)d_in[6];
    const float* b2 = (const float*)d_in[7];
    float* out = (float*)d_out;

    const int* srcIdx = ei;
    const int* dstIdx = ei + N_EDGES;

    size_t off = 0;
    auto alloc = [&](size_t bytes) -> void* {
        void* p = (char*)d_ws + off;
        off += (bytes + 511) & ~(size_t)511;
        return p;
    };
    int* rowStart   = (int*)alloc((size_t)(N_NODES + 1) * 4);
    int* colIdx     = (int*)alloc((size_t)N_EDGES * 4);
    int* staged     = (int*)alloc((size_t)N_EDGES * 4);
    int* bbc        = (int*)alloc((size_t)NBUCK * NCHUNK * 4);
    int* bucketOff  = (int*)alloc((size_t)(NBUCK + 1) * 4);
    float* normv    = (float*)alloc((size_t)N_NODES * 4);
    float* Wc       = (float*)alloc((size_t)256 * 128 * 4);
    float* bc       = (float*)alloc((size_t)128 * 4);
    _Float16* Wcth  = (_Float16*)alloc((size_t)128 * 256 * 2);
    _Float16* Wctl  = (_Float16*)alloc((size_t)128 * 256 * 2);
    _Float16* W2th  = (_Float16*)alloc((size_t)128 * 128 * 2);
    _Float16* W2tl  = (_Float16*)alloc((size_t)128 * 128 * 2);
    _Float16* zA    = (_Float16*)alloc((size_t)N_NODES * 128 * 2);
    _Float16* zB    = (_Float16*)alloc((size_t)N_NODES * 128 * 2);

    const int GB = (N_NODES + 127) / 128;  // 782
    const int AB = (N_NODES + 3) / 4;      // 25000

    // ---- CSR build (bucketed counting sort) ----
    b1_hist<<<NCHUNK, 256, 0, stream>>>(dstIdx, bbc);
    b_scan<<<1, 256, 0, stream>>>(bbc, bucketOff, rowStart);
    b2_scatter<<<NCHUNK, 256, 0, stream>>>(srcIdx, dstIdx, bbc, bucketOff, staged);
    b3_sort<<<NBUCK, 256, 0, stream>>>(staged, bucketOff, rowStart, normv, colIdx);

    // ---- weight prep ----
    wc_kernel<<<257, 128, 0, stream>>>(Wp, bp, W1, Wc, bc);
    tsplit_kernel<<<(256 * 128 + 255) / 256, 256, 0, stream>>>(Wc, Wcth, Wctl, 256);
    tsplit_kernel<<<(128 * 128 + 255) / 256, 256, 0, stream>>>(W2, W2th, W2tl, 128);

    // ---- pipeline (all intermediates fp16, pre-scaled by norm) ----
    // zA = f16[(x @ Wc + bc) * norm]
    mfma_gemm<false><<<GB, 256, 0, stream>>>(x, nullptr, Wcth, Wctl, bc, normv,
                                             nullptr, zA, N_NODES, 256);
    // zB = f16[relu(norm*(sum zA[src] + zA[self]) + b1)]
    agg_kernel<<<AB, 256, 0, stream>>>(zA, rowStart, colIdx, normv, b1, nullptr, zB, 1);
    // zA (reused) = f16[(zB @ W2) * norm]   — A fp16, 2-product path
    mfma_gemm<true><<<GB, 256, 0, stream>>>(nullptr, zB, W2th, W2tl, nullptr, normv,
                                            nullptr, zA, N_NODES, 128);
    // out = fp32[norm*(sum zA[src] + zA[self]) + b2]
    agg_kernel<<<AB, 256, 0, stream>>>(zA, rowStart, colIdx, normv, b2, out, nullptr, 0);
}